// Round 2
// baseline (99.861 us; speedup 1.0000x reference)
//
#include <hip/hip_runtime.h>

// Static config (matches reference)
#define HP 24
#define WP 24
#define TF 9
#define HW (HP * WP)        // 576
#define DIM 768
#define D4 (DIM / 4)        // 192 float4 per row
#define BATCH 4
#define NBOX 50
#define ROI_L (HP * WP)     // 576
#define NXCD 8

typedef float v4f __attribute__((ext_vector_type(4)));

// ---------------------------------------------------------------------------
// Kernel 1: temporal mean  [B, HW*T, D] -> sp [B, HW, D]
// Non-temporal loads (spatial is read-once), cached store (sp is reused).
// ---------------------------------------------------------------------------
__global__ void __launch_bounds__(256)
temporal_mean_kernel(const float* __restrict__ in, float* __restrict__ sp) {
    int i = blockIdx.x * blockDim.x + threadIdx.x;
    const int total = BATCH * HW * D4;
    if (i >= total) return;
    int d4 = i % D4;
    int rest = i / D4;
    int hw = rest % HW;
    int b = rest / HW;

    const v4f* src =
        (const v4f*)(in + ((size_t)(b * HW * TF + hw * TF)) * DIM) + d4;
    v4f acc = (v4f)(0.f);
#pragma unroll
    for (int t = 0; t < TF; ++t) {
        v4f v = __builtin_nontemporal_load(&src[(size_t)t * D4]);
        acc += v;
    }
    acc *= (1.0f / 9.0f);
    ((v4f*)sp)[i] = acc;
}

// ---------------------------------------------------------------------------
// Kernel 2: ROI gather + mask.
// One block (192 threads) per (b, n, chunk-of-4 l values).
// XCD-swizzled blockIdx: all 144 chunks of a box land on the same XCD so the
// box's sp slice (<=1.7 MB) stays L2-resident. Output streamed with
// non-temporal stores (write-once, no reuse) to avoid evicting sp from L2.
// ---------------------------------------------------------------------------
__global__ void __launch_bounds__(192)
roi_gather_kernel(const float* __restrict__ sp, const float* __restrict__ bboxes,
                  float* __restrict__ out_feat, float* __restrict__ out_mask) {
    const int LCHUNKS = ROI_L / 4;                 // 144
    const int NWG = BATCH * NBOX * LCHUNKS;        // 28800, divisible by 8
    const int CPX = NWG / NXCD;                    // 3600

    // bijective XCD swizzle: hw dispatch does xcd = blockIdx.x % 8;
    // remap so XCD k owns contiguous chunk range [k*CPX, (k+1)*CPX)
    int bid = (blockIdx.x % NXCD) * CPX + blockIdx.x / NXCD;

    int ln = bid % LCHUNKS;
    int rest = bid / LCHUNKS;
    int n = rest % NBOX;
    int b = rest / NBOX;
    int tid = threadIdx.x;          // 0..191

    float4 bb = ((const float4*)bboxes)[b * NBOX + n];
    float cx = bb.x, cy = bb.y, bw = bb.z, bh = bb.w;
    float bwp = bw * 1.2f;
    float bhp = bh * 1.2f;

    // astype(int32) truncates toward zero == C (int) cast
    int col_start = max((int)((cx - bwp * 0.5f) * (float)WP), 0);
    int col_end   = min((int)((cx + bwp * 0.5f) * (float)WP), WP);
    int row_start = max((int)((cy - bhp * 0.5f) * (float)HP), 0);
    int row_end   = min((int)((cy + bhp * 0.5f) * (float)HP), HP);

    // (a+b)/2 then trunc; a,b >= 0 so >>1 is exact
    int col_mid = (col_start + col_end) >> 1;
    int row_mid = (row_start + row_end) >> 1;
    // half_min = MIN_PATCHES/2 = 1
    col_start = min(col_start, max(col_mid - 1, 0));
    col_end   = max(col_end,   min(col_mid + 2, WP));
    row_start = min(row_start, max(row_mid - 1, 0));
    row_end   = max(row_end,   min(row_mid + 2, HP));

    int h = max(row_end - row_start, 0);
    int w = max(col_end - col_start, 0);
    int area = h * w;
    int wsafe = max(w, 1);

    size_t out_base = (size_t)(b * NBOX + n) * ROI_L;  // in rows
    v4f* outf4 = (v4f*)out_feat;

#pragma unroll
    for (int sub = 0; sub < 4; ++sub) {
        int l = ln * 4 + sub;
        bool valid = l < area;
        v4f v = (v4f)(0.f);
        if (valid) {
            int r = row_start + l / wsafe;
            int c = col_start + l % wsafe;
            // when valid, r in [row_start, row_end-1] ⊂ [0,23]; same for c —
            // the reference's clip is a no-op on valid elements.
            const v4f* srow = (const v4f*)sp + (size_t)(b * HW + r * WP + c) * D4;
            v = srow[tid];  // cached: sp is the reused working set
        }
        __builtin_nontemporal_store(v, &outf4[(out_base + l) * D4 + tid]);
        if (tid == 0) {
            // True(=1) = padding
            __builtin_nontemporal_store(valid ? 0.0f : 1.0f, &out_mask[out_base + l]);
        }
    }
}

extern "C" void kernel_launch(void* const* d_in, const int* in_sizes, int n_in,
                              void* d_out, int out_size, void* d_ws, size_t ws_size,
                              hipStream_t stream) {
    const float* spatial = (const float*)d_in[0];   // [B, HW*T, D] fp32
    const float* bboxes  = (const float*)d_in[1];   // [B, N, 4] fp32

    float* sp = (float*)d_ws;                       // [B, HW, D] fp32 (6.9 MB)

    float* out_feat = (float*)d_out;                               // [B,N,L,D]
    float* out_mask = (float*)d_out + (size_t)BATCH * NBOX * ROI_L * DIM;  // [B,N,L]

    {
        int total = BATCH * HW * D4;            // 442368
        int block = 256;
        int grid = (total + block - 1) / block; // 1728
        temporal_mean_kernel<<<grid, block, 0, stream>>>(spatial, sp);
    }
    {
        int grid = BATCH * NBOX * (ROI_L / 4);  // 28800
        roi_gather_kernel<<<grid, 192, 0, stream>>>(sp, bboxes, out_feat, out_mask);
    }
}

// Round 3
// 93.550 us; speedup vs baseline: 1.0675x; 1.0675x over previous
//
#include <hip/hip_runtime.h>

// Static config (matches reference)
#define HP 24
#define WP 24
#define TF 9
#define HW (HP * WP)        // 576
#define DIM 768
#define D4 (DIM / 4)        // 192 float4 per row
#define BATCH 4
#define NBOX 50
#define ROI_L (HP * WP)     // 576

#define MEAN_BLOCKS (BATCH * HW * D4 / 192)   // 2304
#define FILL_BLOCKS (BATCH * NBOX * (ROI_L/4)) // 28800

// Shared geometry helper — EXACT arithmetic of the round-1 passing kernel.
__device__ __forceinline__ void box_geometry(float4 bb, int& row_start, int& col_start,
                                             int& area, int& wsafe) {
    float cx = bb.x, cy = bb.y, bw = bb.z, bh = bb.w;
    float bwp = bw * 1.2f;
    float bhp = bh * 1.2f;

    // astype(int32) truncates toward zero == C (int) cast
    int cs = max((int)((cx - bwp * 0.5f) * (float)WP), 0);
    int ce = min((int)((cx + bwp * 0.5f) * (float)WP), WP);
    int rs = max((int)((cy - bhp * 0.5f) * (float)HP), 0);
    int re = min((int)((cy + bhp * 0.5f) * (float)HP), HP);

    // (a+b)/2 then trunc; a,b >= 0 so >>1 is exact
    int col_mid = (cs + ce) >> 1;
    int row_mid = (rs + re) >> 1;
    // half_min = MIN_PATCHES/2 = 1
    cs = min(cs, max(col_mid - 1, 0));
    ce = max(ce, min(col_mid + 2, WP));
    rs = min(rs, max(row_mid - 1, 0));
    re = max(re, min(row_mid + 2, HP));

    int h = max(re - rs, 0);
    int w = max(ce - cs, 0);
    area = h * w;
    wsafe = max(w, 1);
    row_start = rs;
    col_start = cs;
}

// ---------------------------------------------------------------------------
// Kernel A: fused temporal-mean + zero-fill of invalid rows + mask.
//  - blocks [0, MEAN_BLOCKS): sp[b,hw,d] = mean_t spatial[b, hw*T+t, d]
//  - blocks [MEAN_BLOCKS, +FILL_BLOCKS): write zeros for rows l >= area,
//    write the full mask. Depends only on bboxes, so it streams at fill
//    rate concurrently with the mean's read stream.
// ---------------------------------------------------------------------------
__global__ void __launch_bounds__(192)
mean_fill_kernel(const float* __restrict__ in, const float* __restrict__ bboxes,
                 float* __restrict__ sp, float* __restrict__ out_feat,
                 float* __restrict__ out_mask) {
    int tid = threadIdx.x;  // 0..191
    if (blockIdx.x < MEAN_BLOCKS) {
        int i = blockIdx.x * 192 + tid;     // float4 index into sp
        int d4 = i % D4;
        int rest = i / D4;
        int hw = rest % HW;
        int b = rest / HW;
        const float4* src =
            (const float4*)(in + ((size_t)(b * HW * TF + hw * TF)) * DIM) + d4;
        float4 acc = make_float4(0.f, 0.f, 0.f, 0.f);
#pragma unroll
        for (int t = 0; t < TF; ++t) {
            float4 v = src[(size_t)t * D4];
            acc.x += v.x; acc.y += v.y; acc.z += v.z; acc.w += v.w;
        }
        acc.x /= 9.0f; acc.y /= 9.0f; acc.z /= 9.0f; acc.w /= 9.0f;
        ((float4*)sp)[i] = acc;
        return;
    }

    int bid = blockIdx.x - MEAN_BLOCKS;   // [0, FILL_BLOCKS)
    const int LCHUNKS = ROI_L / 4;        // 144
    int ln = bid % LCHUNKS;
    int rest = bid / LCHUNKS;
    int n = rest % NBOX;
    int b = rest / NBOX;

    float4 bb = ((const float4*)bboxes)[b * NBOX + n];
    int row_start, col_start, area, wsafe;
    box_geometry(bb, row_start, col_start, area, wsafe);

    size_t out_base = (size_t)(b * NBOX + n) * ROI_L;  // in rows
    float4* outf4 = (float4*)out_feat;
    const float4 z = make_float4(0.f, 0.f, 0.f, 0.f);

#pragma unroll
    for (int sub = 0; sub < 4; ++sub) {
        int l = ln * 4 + sub;
        bool valid = l < area;            // block-uniform
        if (!valid) {
            outf4[(out_base + l) * D4 + tid] = z;
        }
        if (tid == 0) {
            out_mask[out_base + l] = valid ? 0.0f : 1.0f;  // True(=1) = padding
        }
    }
}

// ---------------------------------------------------------------------------
// Kernel B: gather-only — write the valid rows (l < area) from sp.
// Invalid rows were already zero-filled by kernel A.
// ---------------------------------------------------------------------------
__global__ void __launch_bounds__(192)
roi_gather_kernel(const float* __restrict__ sp, const float* __restrict__ bboxes,
                  float* __restrict__ out_feat) {
    const int LCHUNKS = ROI_L / 4;  // 144
    int bid = blockIdx.x;
    int ln = bid % LCHUNKS;
    int rest = bid / LCHUNKS;
    int n = rest % NBOX;
    int b = rest / NBOX;
    int tid = threadIdx.x;          // 0..191

    float4 bb = ((const float4*)bboxes)[b * NBOX + n];
    int row_start, col_start, area, wsafe;
    box_geometry(bb, row_start, col_start, area, wsafe);

    // whole block's l-range invalid -> nothing to do
    if (ln * 4 >= area) return;

    size_t out_base = (size_t)(b * NBOX + n) * ROI_L;  // in rows
    float4* outf4 = (float4*)out_feat;

#pragma unroll
    for (int sub = 0; sub < 4; ++sub) {
        int l = ln * 4 + sub;
        if (l < area) {
            int r = row_start + l / wsafe;
            int c = col_start + l % wsafe;
            // valid => r,c already in-bounds; reference clip is a no-op here
            const float4* srow =
                (const float4*)sp + (size_t)(b * HW + r * WP + c) * D4;
            outf4[(out_base + l) * D4 + tid] = srow[tid];
        }
    }
}

extern "C" void kernel_launch(void* const* d_in, const int* in_sizes, int n_in,
                              void* d_out, int out_size, void* d_ws, size_t ws_size,
                              hipStream_t stream) {
    const float* spatial = (const float*)d_in[0];   // [B, HW*T, D] fp32
    const float* bboxes  = (const float*)d_in[1];   // [B, N, 4] fp32

    float* sp = (float*)d_ws;                       // [B, HW, D] fp32 (6.9 MB)

    float* out_feat = (float*)d_out;                               // [B,N,L,D]
    float* out_mask = (float*)d_out + (size_t)BATCH * NBOX * ROI_L * DIM;  // [B,N,L]

    {
        int grid = MEAN_BLOCKS + FILL_BLOCKS;   // 31104
        mean_fill_kernel<<<grid, 192, 0, stream>>>(spatial, bboxes, sp,
                                                   out_feat, out_mask);
    }
    {
        int grid = FILL_BLOCKS;                 // 28800
        roi_gather_kernel<<<grid, 192, 0, stream>>>(sp, bboxes, out_feat);
    }
}